// Round 12
// baseline (378.071 us; speedup 1.0000x reference)
//
#include <hip/hip_runtime.h>

typedef unsigned short ushort_t;
typedef unsigned int uint_t;
typedef _Float16 f16_t;
typedef _Float16 half2_t __attribute__((ext_vector_type(2)));
typedef _Float16 half8_t __attribute__((ext_vector_type(8)));
typedef float floatx4 __attribute__((ext_vector_type(4)));
typedef unsigned int uintx4 __attribute__((ext_vector_type(4)));

__device__ __forceinline__ ushort_t f2h_bits(float f) {
    f16_t h = (f16_t)f;
    return __builtin_bit_cast(ushort_t, h);
}
__device__ __forceinline__ float h2f(ushort_t u) {
    return (float)__builtin_bit_cast(f16_t, u);
}
__device__ __forceinline__ float h2f_lo(uint_t u) { return h2f((ushort_t)(u & 0xFFFF)); }
__device__ __forceinline__ float h2f_hi(uint_t u) { return h2f((ushort_t)(u >> 16)); }
__device__ __forceinline__ float sigm(float x) { return 1.0f / (1.0f + __expf(-x)); }
__device__ __forceinline__ float tanhx(float x) {
    x = fminf(fmaxf(x, -15.0f), 15.0f);
    float e = __expf(2.0f * x);
    return (e - 1.0f) / (e + 1.0f);
}
__device__ __forceinline__ half8_t h8(uint4 v) { return __builtin_bit_cast(half8_t, v); }

// B-fragment layout everywhere: frag(kt,q,n) at halves ((kt*4+q)*V + n)*8 + j,
// holding B[k][n] with k = kt*32 + q*8 + j. Consecutive n -> contiguous b128.
__device__ __forceinline__ void pack_one(
    const float* srcA, int KA, const float* srcB, int KB,
    ushort_t* dst, int V, int K, int idx)
{
    int v = idx / K, k = idx - v * K;
    float val = 0.0f;
    if (k < KA) val = srcA[v * KA + k];
    else if (k < KA + KB) val = srcB[v * KB + (k - KA)];
    int kt = k >> 5, qq = (k >> 3) & 3, j = k & 7;
    dst[((size_t)((kt * 4 + qq) * V + v)) * 8 + j] = f2h_bits(val);
}

// t-LSTM variant: V=768, skip dead f-gate rows (src row = v<256 ? v : v+256).
__device__ __forceinline__ void pack_tl_one(
    const float* src, int Ksrc, ushort_t* dst, int K, int idx)
{
    int v = idx / K, k = idx - v * K;
    int r = (v < 256) ? v : v + 256;
    float val = (k < Ksrc) ? src[r * Ksrc + k] : 0.0f;
    int kt = k >> 5, qq = (k >> 3) & 3, j = k & 7;
    dst[((size_t)((kt * 4 + qq) * 768 + v)) * 8 + j] = f2h_bits(val);
}

// All 5 weight packs fused into one launch.
__global__ __launch_bounds__(256) void packAll(
    const float* __restrict__ tWih0, const float* __restrict__ tWih1,
    const float* __restrict__ nWih0, const float* __restrict__ nWhh0,
    const float* __restrict__ nWih1, const float* __restrict__ nWhh1,
    ushort_t* __restrict__ W0m, ushort_t* __restrict__ W1m,
    ushort_t* __restrict__ N0x, ushort_t* __restrict__ N0m,
    ushort_t* __restrict__ N1m)
{
    int idx = blockIdx.x * 256 + threadIdx.x;
    if (idx < 49152) { pack_tl_one(tWih0, 50, W0m, 64, idx); return; }
    idx -= 49152;
    if (idx < 196608) { pack_tl_one(tWih1, 256, W1m, 256, idx); return; }
    idx -= 196608;
    if (idx < 131072) { pack_one(nWih0, 257, (const float*)0, 0, N0x, 512, 256, idx); return; }
    idx -= 131072;
    if (idx < 65536) { pack_one(nWhh0, 128, (const float*)0, 0, N0m, 512, 128, idx); return; }
    idx -= 65536;
    if (idx < 131072) { pack_one(nWih1, 128, nWhh1, 128, N1m, 512, 256, idx); return; }
}

// fusedA: 3-GEMM MFMA kernel, 768 blocks x 64 rows — R12: explicit software
// pipelines for all B-frag L2 loads (the 128-VGPR cap kept them in-loop,
// exposing ~300 cyc latency per load group; ~130 us of the ~160 us runtime).
// GEMM1 frags fully preloaded pre-barrier; GEMM2 flat 16-pair loop with
// 2-slot distance-2 prefetch (no s-boundary bubble); GEMM3 2-slot pipeline.
// FP order identical to R11 (absmax preserved).
__global__ __launch_bounds__(512, 2) void fusedA(
    const float* __restrict__ note, const float* __restrict__ targets,
    const ushort_t* __restrict__ W0m, const float* __restrict__ b0,
    const ushort_t* __restrict__ W1m, const float* __restrict__ b1,
    const ushort_t* __restrict__ N0x, const float* __restrict__ nWih0raw,
    const float* __restrict__ nb0,
    uint_t* __restrict__ G1u)
{
    __shared__ __align__(16) ushort_t xAa[64 * 64];
    __shared__ __align__(16) ushort_t xH1[64 * 256];
    __shared__ __align__(16) ushort_t xH2[64 * 256];
    const int tid = threadIdx.x;
    const int wv = tid >> 6, l = tid & 63, l16 = l & 15, q = l >> 4;
    const int r0A = blockIdx.x * 64;

    // ---- GEMM1 B-frags: fully preloaded; drain for free at staging barrier
    uint4 B1[2][2][3];
#pragma unroll
    for (int s = 0; s < 2; ++s) {
        int u = (wv * 2 + s) * 16 + l16;
#pragma unroll
        for (int kt = 0; kt < 2; ++kt) {
            size_t base = ((size_t)((kt * 4 + q) * 768 + u)) * 8;
            B1[s][kt][0] = *(const uint4*)(W0m + base);
            B1[s][kt][1] = *(const uint4*)(W0m + base + 256 * 8);
            B1[s][kt][2] = *(const uint4*)(W0m + base + 512 * 8);
        }
    }
    // E-phase biases hoisted (scalar loads drain at barrier too)
    float biG1[2], bgG1[2], boG1[2], biG2[2], bgG2[2], boG2[2];
#pragma unroll
    for (int s = 0; s < 2; ++s) {
        int u = (wv * 2 + s) * 16 + l16;
        biG1[s] = b0[u]; bgG1[s] = b0[512 + u]; boG1[s] = b0[768 + u];
        biG2[s] = b1[u]; bgG2[s] = b1[512 + u]; boG2[s] = b1[768 + u];
    }

    // staging: features (pitch_pos | pitch_class | vicinity | chord), K 56->64
    for (int idx = tid; idx < 64 * 64; idx += 512) {
        int r = idx >> 6, c = idx & 63;
        int row = r0A + r;
        int b = row / 48, n = row - b * 48;
        float val = 0.0f;
        if (c == 0) val = (float)n * (1.0f / 48.0f);
        else if (c < 13) val = ((n % 12) == (c - 1)) ? 1.0f : 0.0f;
        else if (c < 38) {
            int p = n + (c - 13) - 12;
            if (p >= 0 && p < 48) val = note[b * 48 + p];
        } else if (c < 50) {
            const float* nb = note + b * 48 + (c - 38) * 4;
            val = nb[0] + nb[1] + nb[2] + nb[3];
        }
        int kb = c >> 3, j = c & 7;
        xAa[r * 64 + (((kb ^ r) & 7) << 3) + j] = f2h_bits(val);
    }
    __syncthreads();

    // ---- GEMM1 (K=64) + gate -> xH1 (frags already in registers) ----
#pragma unroll
    for (int s = 0; s < 2; ++s) {
        const int u = (wv * 2 + s) * 16 + l16;
        floatx4 acc[4][3] = {};
#pragma unroll
        for (int kt = 0; kt < 2; ++kt) {
            int kbp = ((kt * 4 + q) ^ l16) & 7;
#pragma unroll
            for (int mt = 0; mt < 4; ++mt) {
                half8_t a = *(const half8_t*)&xAa[(mt * 16 + l16) * 64 + kbp * 8];
                acc[mt][0] = __builtin_amdgcn_mfma_f32_16x16x32_f16(a, h8(B1[s][kt][0]), acc[mt][0], 0, 0, 0);
                acc[mt][1] = __builtin_amdgcn_mfma_f32_16x16x32_f16(a, h8(B1[s][kt][1]), acc[mt][1], 0, 0, 0);
                acc[mt][2] = __builtin_amdgcn_mfma_f32_16x16x32_f16(a, h8(B1[s][kt][2]), acc[mt][2], 0, 0, 0);
            }
        }
        int kbW = u >> 3;
#pragma unroll
        for (int mt = 0; mt < 4; ++mt)
#pragma unroll
            for (int r = 0; r < 4; ++r) {
                float c = sigm(acc[mt][0][r] + biG1[s]) * tanhx(acc[mt][1][r] + bgG1[s]);
                float h = sigm(acc[mt][2][r] + boG1[s]) * tanhx(c);
                int m = mt * 16 + q * 4 + r;
                int kbp = (kbW & 16) | ((kbW ^ (m & 15)) & 15);
                xH1[m * 256 + kbp * 8 + (u & 7)] = f2h_bits(h);
            }
    }

    // GEMM2 stage slots: prefetch pairs 0,1 (s=0,kt=0/1) BEFORE the barrier
    uint4 S2[2][3];
    {
        int u0 = (wv * 2) * 16 + l16;
#pragma unroll
        for (int sl = 0; sl < 2; ++sl) {
            size_t base = ((size_t)((sl * 4 + q) * 768 + u0)) * 8;
            S2[sl][0] = *(const uint4*)(W1m + base);
            S2[sl][1] = *(const uint4*)(W1m + base + 256 * 8);
            S2[sl][2] = *(const uint4*)(W1m + base + 512 * 8);
        }
    }
    __syncthreads();

    // ---- GEMM2 (K=256) + gate -> xH2: flat 16-pair loop, distance-2 pipe ----
    {
        floatx4 acc[4][3] = {};
#pragma unroll
        for (int p = 0; p < 16; ++p) {
            const int s = p >> 3, kt = p & 7, sl = p & 1;
            const int u = (wv * 2 + s) * 16 + l16;
            half8_t bI = h8(S2[sl][0]), bG = h8(S2[sl][1]), bO = h8(S2[sl][2]);
            int kb = kt * 4 + q;
            int kbp = (kb & 16) | ((kb ^ l16) & 15);
#pragma unroll
            for (int mt = 0; mt < 4; ++mt) {
                half8_t a = *(const half8_t*)&xH1[(mt * 16 + l16) * 256 + kbp * 8];
                acc[mt][0] = __builtin_amdgcn_mfma_f32_16x16x32_f16(a, bI, acc[mt][0], 0, 0, 0);
                acc[mt][1] = __builtin_amdgcn_mfma_f32_16x16x32_f16(a, bG, acc[mt][1], 0, 0, 0);
                acc[mt][2] = __builtin_amdgcn_mfma_f32_16x16x32_f16(a, bO, acc[mt][2], 0, 0, 0);
            }
            if (p < 14) {   // prefetch pair p+2 into the slot just consumed
                const int pn = p + 2, sn = pn >> 3, ktn = pn & 7;
                const int un = (wv * 2 + sn) * 16 + l16;
                size_t base = ((size_t)((ktn * 4 + q) * 768 + un)) * 8;
                S2[sl][0] = *(const uint4*)(W1m + base);
                S2[sl][1] = *(const uint4*)(W1m + base + 256 * 8);
                S2[sl][2] = *(const uint4*)(W1m + base + 512 * 8);
            }
            if (kt == 7) {  // E-phase for this s, then reset acc
                const int uu = (wv * 2 + s) * 16 + l16;
                int kbW = uu >> 3;
#pragma unroll
                for (int mt = 0; mt < 4; ++mt)
#pragma unroll
                    for (int r = 0; r < 4; ++r) {
                        float c = sigm(acc[mt][0][r] + biG2[s]) * tanhx(acc[mt][1][r] + bgG2[s]);
                        float h = sigm(acc[mt][2][r] + boG2[s]) * tanhx(c);
                        int m = mt * 16 + q * 4 + r;
                        int kbp2 = (kbW & 16) | ((kbW ^ (m & 15)) & 15);
                        xH2[m * 256 + kbp2 * 8 + (uu & 7)] = f2h_bits(h);
                        acc[mt][0][r] = 0.0f; acc[mt][1][r] = 0.0f; acc[mt][2][r] = 0.0f;
                    }
            }
        }
    }

    // GEMM3 stage slots: prefetch kt=0,1 (4 gates each) BEFORE the barrier
    const int u2 = wv * 16 + l16;
    uint4 S3[2][4];
#pragma unroll
    for (int sl = 0; sl < 2; ++sl) {
        size_t base = ((size_t)((sl * 4 + q) * 512)) * 8;
#pragma unroll
        for (int g = 0; g < 4; ++g)
            S3[sl][g] = *(const uint4*)(N0x + base + ((size_t)(g * 128 + u2)) * 8);
    }
    __syncthreads();

    // ---- GEMM3 (K=256) + bias + cond rank-1 -> G1 ----
    {
        floatx4 acc[4][4] = {};
#pragma unroll
        for (int kt = 0; kt < 8; ++kt) {
            const int sl = kt & 1;
            half8_t bf[4];
#pragma unroll
            for (int g = 0; g < 4; ++g) bf[g] = h8(S3[sl][g]);
            int kb = kt * 4 + q;
            int kbp = (kb & 16) | ((kb ^ l16) & 15);
#pragma unroll
            for (int mt = 0; mt < 4; ++mt) {
                half8_t a = *(const half8_t*)&xH2[(mt * 16 + l16) * 256 + kbp * 8];
#pragma unroll
                for (int g = 0; g < 4; ++g)
                    acc[mt][g] = __builtin_amdgcn_mfma_f32_16x16x32_f16(a, bf[g], acc[mt][g], 0, 0, 0);
            }
            if (kt < 6) {
                size_t base = ((size_t)(((kt + 2) * 4 + q) * 512)) * 8;
#pragma unroll
                for (int g = 0; g < 4; ++g)
                    S3[sl][g] = *(const uint4*)(N0x + base + ((size_t)(g * 128 + u2)) * 8);
            }
        }
        float bias[4], wc[4];
#pragma unroll
        for (int g = 0; g < 4; ++g) {
            bias[g] = nb0[g * 128 + u2];
            wc[g] = nWih0raw[(size_t)(g * 128 + u2) * 257 + 256];
        }
#pragma unroll
        for (int mt = 0; mt < 4; ++mt) {
#pragma unroll
            for (int r = 0; r < 4; ++r) {
                int R = r0A + mt * 16 + q * 4 + r;
                int b = R / 48;
                int t = R - b * 48;
                float cond = (t > 0) ? targets[R - 1] : 0.0f;
                float vi = acc[mt][0][r] + bias[0] + cond * wc[0];
                float vf = acc[mt][1][r] + bias[1] + cond * wc[1];
                float vg = acc[mt][2][r] + bias[2] + cond * wc[2];
                float vo = acc[mt][3][r] + bias[3] + cond * wc[3];
                uint_t lo = (uint_t)f2h_bits(vi) | ((uint_t)f2h_bits(vf) << 16);
                uint_t hi = (uint_t)f2h_bits(vg) | ((uint_t)f2h_bits(vo) << 16);
                size_t a = ((size_t)(b >> 4) * 48 + t) * 4096 + (b & 15) * 256 + u2 * 2;
                *(uint2*)(G1u + a) = make_uint2(lo, hi);
            }
        }
    }
}

// phaseB: reverted verbatim to the K9 variant (190 us, conflicts 0):
// asm-pinned B2 frags, full-XOR xA swizzle, G1 prefetch at loop top,
// inline output head. Six structural experiments bracket this as the floor
// of the 64-block 2-barrier structure.
__global__ __launch_bounds__(512) __attribute__((amdgpu_waves_per_eu(2, 2)))
void phaseB(
    const uint_t* __restrict__ G1u, const ushort_t* __restrict__ N0m,
    const ushort_t* __restrict__ N1m, const float* __restrict__ nb1,
    const float* __restrict__ outW, const float* __restrict__ outb,
    float* __restrict__ out)
{
    __shared__ __align__(16) ushort_t w1s[16 * 512 * 8];  // 131072 B
    __shared__ __align__(16) ushort_t xA[16 * 512];       // [m][h1b0|h1b1|h2b0|h2b1]
    __shared__ __align__(16) float ghead[8][16];
    const int tid = threadIdx.x;
    const int wv = tid >> 6, l = tid & 63, l16 = l & 15, q = l >> 4;
    const int r0 = blockIdx.x * 16;
    const int u = wv * 16 + l16;                 // unit 0..127

    for (int i = tid; i < 8192; i += 512) ((uint4*)w1s)[i] = ((const uint4*)N0m)[i];
    for (int i = tid; i < 1024; i += 512) ((uint4*)xA)[i] = make_uint4(0, 0, 0, 0);

    // persistent L2-layer B-frags (128 VGPRs)
    uintx4 B2[8][4];
#pragma unroll
    for (int kt = 0; kt < 8; ++kt)
#pragma unroll
        for (int g = 0; g < 4; ++g)
            B2[kt][g] = *(const uintx4*)(N1m + ((size_t)((kt * 4 + q) * 512 + g * 128 + u)) * 8);

    const float bI = nb1[u], bF = nb1[128 + u], bG = nb1[256 + u], bO = nb1[384 + u];
    const float ob = outb[0];
    const float owf = outW[u];
    float c1[4] = {0, 0, 0, 0}, c2[4] = {0, 0, 0, 0};

    const uint_t* g1base = G1u + (size_t)blockIdx.x * 48 * 4096;
    uint2 g1c[4], g1n[4];
#pragma unroll
    for (int r = 0; r < 4; ++r)
        g1c[r] = *(const uint2*)(g1base + (q * 4 + r) * 256 + u * 2);
    __syncthreads();

    const int kbW = u >> 3;   // 0..15
    const int jW = u & 7;

    for (int t = 0; t < 48; ++t) {
        const int cur = (t & 1) * 128;
        const int prv = cur ^ 128;

        // Residency pin: asm "modifies" B2 each iteration -> reload illegal.
#pragma unroll
        for (int kt = 0; kt < 8; ++kt)
#pragma unroll
            for (int g = 0; g < 4; ++g)
                asm volatile("" : "+v"(B2[kt][g]));

        // G1 prefetch for t+1 at loop top
        {
            int tn = (t < 47) ? t + 1 : 47;
            const uint_t* gp = g1base + (size_t)tn * 4096;
#pragma unroll
            for (int r = 0; r < 4; ++r)
                g1n[r] = *(const uint2*)(gp + (q * 4 + r) * 256 + u * 2);
        }

        // L1 MFMA: gates = Whh0 @ h1(t-1); A from xA[prv], B from LDS
        floatx4 acc[4] = {};
#pragma unroll
        for (int kt = 0; kt < 4; ++kt) {
            int kb = kt * 4 + q;
            int kbp = (kb ^ l16) & 15;
            half8_t a = *(const half8_t*)&xA[l16 * 512 + prv + kbp * 8];
#pragma unroll
            for (int g = 0; g < 4; ++g) {
                half8_t bfr = *(const half8_t*)&w1s[((size_t)(kb * 512 + g * 128 + u)) * 8];
                acc[g] = __builtin_amdgcn_mfma_f32_16x16x32_f16(a, bfr, acc[g], 0, 0, 0);
            }
        }
        // E1: gate + write h1(t) into buf cur
#pragma unroll
        for (int r = 0; r < 4; ++r) {
            float gi = acc[0][r] + h2f_lo(g1c[r].x);
            float gf = acc[1][r] + h2f_hi(g1c[r].x);
            float gg = acc[2][r] + h2f_lo(g1c[r].y);
            float go = acc[3][r] + h2f_hi(g1c[r].y);
            c1[r] = sigm(gf) * c1[r] + sigm(gi) * tanhx(gg);
            float h1 = sigm(go) * tanhx(c1[r]);
            int m = q * 4 + r;
            xA[m * 512 + cur + (((kbW ^ m) & 15) << 3) + jW] = f2h_bits(h1);
        }
        // L2 MFMA part A: kt 4..7 = h2(t-1) from xA[256+prv]
        floatx4 acc2[4] = {};
#pragma unroll
        for (int kt = 4; kt < 8; ++kt) {
            int kbr = (kt & 3) * 4 + q;
            int kbp = (kbr ^ l16) & 15;
            half8_t a = *(const half8_t*)&xA[l16 * 512 + 256 + prv + kbp * 8];
#pragma unroll
            for (int g = 0; g < 4; ++g)
                acc2[g] = __builtin_amdgcn_mfma_f32_16x16x32_f16(
                    a, __builtin_bit_cast(half8_t, B2[kt][g]), acc2[g], 0, 0, 0);
        }
        __syncthreads();   // #1: h1(t) visible

        // L2 MFMA part B: kt 0..3 = h1(t) from xA[cur]
#pragma unroll
        for (int kt = 0; kt < 4; ++kt) {
            int kb = kt * 4 + q;
            int kbp = (kb ^ l16) & 15;
            half8_t a = *(const half8_t*)&xA[l16 * 512 + cur + kbp * 8];
#pragma unroll
            for (int g = 0; g < 4; ++g)
                acc2[g] = __builtin_amdgcn_mfma_f32_16x16x32_f16(
                    a, __builtin_bit_cast(half8_t, B2[kt][g]), acc2[g], 0, 0, 0);
        }
        // E2: gate + write h2(t) + head partial from registers
        float p[4];
#pragma unroll
        for (int r = 0; r < 4; ++r) {
            float gi = acc2[0][r] + bI;
            float gf = acc2[1][r] + bF;
            float gg = acc2[2][r] + bG;
            float go = acc2[3][r] + bO;
            c2[r] = sigm(gf) * c2[r] + sigm(gi) * tanhx(gg);
            float h2 = sigm(go) * tanhx(c2[r]);
            int m = q * 4 + r;
            xA[m * 512 + 256 + cur + (((kbW ^ m) & 15) << 3) + jW] = f2h_bits(h2);
            p[r] = h2 * owf;
        }
#pragma unroll
        for (int mask = 1; mask < 16; mask <<= 1)
#pragma unroll
            for (int r = 0; r < 4; ++r) p[r] += __shfl_xor(p[r], mask, 64);
        if (l16 == 0) {
#pragma unroll
            for (int r = 0; r < 4; ++r) ghead[wv][q * 4 + r] = p[r];
        }
#pragma unroll
        for (int r = 0; r < 4; ++r) g1c[r] = g1n[r];
        __syncthreads();   // #2: h2(t) + ghead visible

        if (tid < 16) {
            float s = 0.0f;
#pragma unroll
            for (int w = 0; w < 8; ++w) s += ghead[w][tid];
            out[(r0 + tid) * 48 + t] = sigm(s + ob);
        }
    }
}

extern "C" void kernel_launch(void* const* d_in, const int* in_sizes, int n_in,
                              void* d_out, int out_size, void* d_ws, size_t ws_size,
                              hipStream_t stream)
{
    const float* note  = (const float*)d_in[0];
    const float* targ  = (const float*)d_in[1];
    const float* tWih0 = (const float*)d_in[2];
    const float* tb0   = (const float*)d_in[4];
    const float* tWih1 = (const float*)d_in[5];
    const float* tb1   = (const float*)d_in[7];
    const float* nWih0 = (const float*)d_in[8];
    const float* nWhh0 = (const float*)d_in[9];
    const float* nb0   = (const float*)d_in[10];
    const float* nWih1 = (const float*)d_in[11];
    const float* nWhh1 = (const float*)d_in[12];
    const float* nb1   = (const float*)d_in[13];
    const float* outW  = (const float*)d_in[14];
    const float* outb  = (const float*)d_in[15];

    char* ws = (char*)d_ws;
    uint_t*   G1u = (uint_t*)(ws);                // 64*48*4096 uints = 50331648 B
    ushort_t* W0m = (ushort_t*)(ws + 50331648);   //  98304 B
    ushort_t* W1m = (ushort_t*)(ws + 50429952);   // 393216 B
    ushort_t* N0x = (ushort_t*)(ws + 50823168);   // 262144 B
    ushort_t* N0m = (ushort_t*)(ws + 51085312);   // 131072 B
    ushort_t* N1m = (ushort_t*)(ws + 51216384);   // 262144 B

    packAll<<<2240, 256, 0, stream>>>(tWih0, tWih1, nWih0, nWhh0, nWih1, nWhh1,
                                      W0m, W1m, N0x, N0m, N1m);
    fusedA<<<768, 512, 0, stream>>>(note, targ, W0m, tb0, W1m, tb1, N0x, nWih0, nb0, G1u);
    phaseB<<<64, 512, 0, stream>>>(G1u, N0m, N1m, nb1, outW, outb, (float*)d_out);
}

// Round 13
// 366.519 us; speedup vs baseline: 1.0315x; 1.0315x over previous
//
#include <hip/hip_runtime.h>

typedef unsigned short ushort_t;
typedef unsigned int uint_t;
typedef _Float16 f16_t;
typedef _Float16 half2_t __attribute__((ext_vector_type(2)));
typedef _Float16 half8_t __attribute__((ext_vector_type(8)));
typedef float floatx4 __attribute__((ext_vector_type(4)));
typedef unsigned int uintx4 __attribute__((ext_vector_type(4)));

__device__ __forceinline__ ushort_t f2h_bits(float f) {
    f16_t h = (f16_t)f;
    return __builtin_bit_cast(ushort_t, h);
}
__device__ __forceinline__ float h2f(ushort_t u) {
    return (float)__builtin_bit_cast(f16_t, u);
}
__device__ __forceinline__ float h2f_lo(uint_t u) { return h2f((ushort_t)(u & 0xFFFF)); }
__device__ __forceinline__ float h2f_hi(uint_t u) { return h2f((ushort_t)(u >> 16)); }
__device__ __forceinline__ float sigm(float x) { return 1.0f / (1.0f + __expf(-x)); }
__device__ __forceinline__ float tanhx(float x) {
    x = fminf(fmaxf(x, -15.0f), 15.0f);
    float e = __expf(2.0f * x);
    return (e - 1.0f) / (e + 1.0f);
}
__device__ __forceinline__ half8_t h8(uint4 v) { return __builtin_bit_cast(half8_t, v); }

// B-fragment layout everywhere: frag(kt,q,n) at halves ((kt*4+q)*V + n)*8 + j,
// holding B[k][n] with k = kt*32 + q*8 + j. Consecutive n -> contiguous b128.
__device__ __forceinline__ half8_t ldfrag(const ushort_t* p, int V, int kt, int q, int n) {
    return *(const half8_t*)(p + ((size_t)((kt * 4 + q) * V + n)) * 8);
}

__device__ __forceinline__ void pack_one(
    const float* srcA, int KA, const float* srcB, int KB,
    ushort_t* dst, int V, int K, int idx)
{
    int v = idx / K, k = idx - v * K;
    float val = 0.0f;
    if (k < KA) val = srcA[v * KA + k];
    else if (k < KA + KB) val = srcB[v * KB + (k - KA)];
    int kt = k >> 5, qq = (k >> 3) & 3, j = k & 7;
    dst[((size_t)((kt * 4 + qq) * V + v)) * 8 + j] = f2h_bits(val);
}

// t-LSTM variant: V=768, skip dead f-gate rows (src row = v<256 ? v : v+256).
__device__ __forceinline__ void pack_tl_one(
    const float* src, int Ksrc, ushort_t* dst, int K, int idx)
{
    int v = idx / K, k = idx - v * K;
    int r = (v < 256) ? v : v + 256;
    float val = (k < Ksrc) ? src[r * Ksrc + k] : 0.0f;
    int kt = k >> 5, qq = (k >> 3) & 3, j = k & 7;
    dst[((size_t)((kt * 4 + qq) * 768 + v)) * 8 + j] = f2h_bits(val);
}

// All 5 weight packs fused into one launch.
__global__ __launch_bounds__(256) void packAll(
    const float* __restrict__ tWih0, const float* __restrict__ tWih1,
    const float* __restrict__ nWih0, const float* __restrict__ nWhh0,
    const float* __restrict__ nWih1, const float* __restrict__ nWhh1,
    ushort_t* __restrict__ W0m, ushort_t* __restrict__ W1m,
    ushort_t* __restrict__ N0x, ushort_t* __restrict__ N0m,
    ushort_t* __restrict__ N1m)
{
    int idx = blockIdx.x * 256 + threadIdx.x;
    if (idx < 49152) { pack_tl_one(tWih0, 50, W0m, 64, idx); return; }
    idx -= 49152;
    if (idx < 196608) { pack_tl_one(tWih1, 256, W1m, 256, idx); return; }
    idx -= 196608;
    if (idx < 131072) { pack_one(nWih0, 257, (const float*)0, 0, N0x, 512, 256, idx); return; }
    idx -= 131072;
    if (idx < 65536) { pack_one(nWhh0, 128, (const float*)0, 0, N0m, 512, 128, idx); return; }
    idx -= 65536;
    if (idx < 131072) { pack_one(nWih1, 128, nWhh1, 128, N1m, 512, 256, idx); return; }
}

// fusedA R13: 32-row M-tiles (1536 blocks), LDS 36 kB -> 3 blocks/CU possible,
// __launch_bounds__(512,6) targets ~85 VGPRs -> 24 waves/CU (+50% TLP vs 16).
// Per-wave critical work halved (mt 4->2). Simple in-loop loads (R12 proved
// pipelining neutral); smaller code also relieves I$.
__global__ __launch_bounds__(512, 6) void fusedA(
    const float* __restrict__ note, const float* __restrict__ targets,
    const ushort_t* __restrict__ W0m, const float* __restrict__ b0,
    const ushort_t* __restrict__ W1m, const float* __restrict__ b1,
    const ushort_t* __restrict__ N0x, const float* __restrict__ nWih0raw,
    const float* __restrict__ nb0,
    uint_t* __restrict__ G1u)
{
    __shared__ __align__(16) ushort_t xAa[32 * 64];
    __shared__ __align__(16) ushort_t xH1[32 * 256];
    __shared__ __align__(16) ushort_t xH2[32 * 256];
    const int tid = threadIdx.x;
    const int wv = tid >> 6, l = tid & 63, l16 = l & 15, q = l >> 4;
    const int r0A = blockIdx.x * 32;

    // staging: features (pitch_pos | pitch_class | vicinity | chord), K 56->64
    for (int idx = tid; idx < 32 * 64; idx += 512) {
        int r = idx >> 6, c = idx & 63;
        int row = r0A + r;
        int b = row / 48, n = row - b * 48;
        float val = 0.0f;
        if (c == 0) val = (float)n * (1.0f / 48.0f);
        else if (c < 13) val = ((n % 12) == (c - 1)) ? 1.0f : 0.0f;
        else if (c < 38) {
            int p = n + (c - 13) - 12;
            if (p >= 0 && p < 48) val = note[b * 48 + p];
        } else if (c < 50) {
            const float* nb = note + b * 48 + (c - 38) * 4;
            val = nb[0] + nb[1] + nb[2] + nb[3];
        }
        int kb = c >> 3, j = c & 7;
        xAa[r * 64 + (((kb ^ r) & 7) << 3) + j] = f2h_bits(val);
    }
    __syncthreads();

    // ---- GEMM1 (K=64) + gate -> xH1 ----
#pragma unroll
    for (int s = 0; s < 2; ++s) {
        const int u = (wv * 2 + s) * 16 + l16;
        floatx4 acc[2][3] = {};
#pragma unroll
        for (int kt = 0; kt < 2; ++kt) {
            half8_t bI = ldfrag(W0m, 768, kt, q, u);
            half8_t bG = ldfrag(W0m, 768, kt, q, 256 + u);
            half8_t bO = ldfrag(W0m, 768, kt, q, 512 + u);
            int kbp = ((kt * 4 + q) ^ l16) & 7;
#pragma unroll
            for (int mt = 0; mt < 2; ++mt) {
                half8_t a = *(const half8_t*)&xAa[(mt * 16 + l16) * 64 + kbp * 8];
                acc[mt][0] = __builtin_amdgcn_mfma_f32_16x16x32_f16(a, bI, acc[mt][0], 0, 0, 0);
                acc[mt][1] = __builtin_amdgcn_mfma_f32_16x16x32_f16(a, bG, acc[mt][1], 0, 0, 0);
                acc[mt][2] = __builtin_amdgcn_mfma_f32_16x16x32_f16(a, bO, acc[mt][2], 0, 0, 0);
            }
        }
        float bi = b0[u], bg = b0[512 + u], bo = b0[768 + u];
        int kbW = u >> 3;
#pragma unroll
        for (int mt = 0; mt < 2; ++mt)
#pragma unroll
            for (int r = 0; r < 4; ++r) {
                float c = sigm(acc[mt][0][r] + bi) * tanhx(acc[mt][1][r] + bg);
                float h = sigm(acc[mt][2][r] + bo) * tanhx(c);
                int m = mt * 16 + q * 4 + r;
                int kbp = (kbW & 16) | ((kbW ^ (m & 15)) & 15);
                xH1[m * 256 + kbp * 8 + (u & 7)] = f2h_bits(h);
            }
    }
    __syncthreads();

    // ---- GEMM2 (K=256) + gate -> xH2 ----
#pragma unroll
    for (int s = 0; s < 2; ++s) {
        const int u = (wv * 2 + s) * 16 + l16;
        floatx4 acc[2][3] = {};
#pragma unroll
        for (int kt = 0; kt < 8; ++kt) {
            half8_t bI = ldfrag(W1m, 768, kt, q, u);
            half8_t bG = ldfrag(W1m, 768, kt, q, 256 + u);
            half8_t bO = ldfrag(W1m, 768, kt, q, 512 + u);
            int kb = kt * 4 + q;
            int kbp = (kb & 16) | ((kb ^ l16) & 15);
#pragma unroll
            for (int mt = 0; mt < 2; ++mt) {
                half8_t a = *(const half8_t*)&xH1[(mt * 16 + l16) * 256 + kbp * 8];
                acc[mt][0] = __builtin_amdgcn_mfma_f32_16x16x32_f16(a, bI, acc[mt][0], 0, 0, 0);
                acc[mt][1] = __builtin_amdgcn_mfma_f32_16x16x32_f16(a, bG, acc[mt][1], 0, 0, 0);
                acc[mt][2] = __builtin_amdgcn_mfma_f32_16x16x32_f16(a, bO, acc[mt][2], 0, 0, 0);
            }
        }
        float bi = b1[u], bg = b1[512 + u], bo = b1[768 + u];
        int kbW = u >> 3;
#pragma unroll
        for (int mt = 0; mt < 2; ++mt)
#pragma unroll
            for (int r = 0; r < 4; ++r) {
                float c = sigm(acc[mt][0][r] + bi) * tanhx(acc[mt][1][r] + bg);
                float h = sigm(acc[mt][2][r] + bo) * tanhx(c);
                int m = mt * 16 + q * 4 + r;
                int kbp = (kbW & 16) | ((kbW ^ (m & 15)) & 15);
                xH2[m * 256 + kbp * 8 + (u & 7)] = f2h_bits(h);
            }
    }
    __syncthreads();

    // ---- GEMM3 (K=256) + bias + cond rank-1 -> G1 (coalesced uint2 stores) ----
    {
        const int u2 = wv * 16 + l16;
        floatx4 acc[2][4] = {};
#pragma unroll
        for (int kt = 0; kt < 8; ++kt) {
            half8_t bf[4];
#pragma unroll
            for (int g = 0; g < 4; ++g) bf[g] = ldfrag(N0x, 512, kt, q, g * 128 + u2);
            int kb = kt * 4 + q;
            int kbp = (kb & 16) | ((kb ^ l16) & 15);
#pragma unroll
            for (int mt = 0; mt < 2; ++mt) {
                half8_t a = *(const half8_t*)&xH2[(mt * 16 + l16) * 256 + kbp * 8];
#pragma unroll
                for (int g = 0; g < 4; ++g)
                    acc[mt][g] = __builtin_amdgcn_mfma_f32_16x16x32_f16(a, bf[g], acc[mt][g], 0, 0, 0);
            }
        }
        float bias[4], wc[4];
#pragma unroll
        for (int g = 0; g < 4; ++g) {
            bias[g] = nb0[g * 128 + u2];
            wc[g] = nWih0raw[(size_t)(g * 128 + u2) * 257 + 256];
        }
#pragma unroll
        for (int mt = 0; mt < 2; ++mt) {
#pragma unroll
            for (int r = 0; r < 4; ++r) {
                int R = r0A + mt * 16 + q * 4 + r;
                int b = R / 48;
                int t = R - b * 48;
                float cond = (t > 0) ? targets[R - 1] : 0.0f;
                float vi = acc[mt][0][r] + bias[0] + cond * wc[0];
                float vf = acc[mt][1][r] + bias[1] + cond * wc[1];
                float vg = acc[mt][2][r] + bias[2] + cond * wc[2];
                float vo = acc[mt][3][r] + bias[3] + cond * wc[3];
                uint_t lo = (uint_t)f2h_bits(vi) | ((uint_t)f2h_bits(vf) << 16);
                uint_t hi = (uint_t)f2h_bits(vg) | ((uint_t)f2h_bits(vo) << 16);
                size_t a = ((size_t)(b >> 4) * 48 + t) * 4096 + (b & 15) * 256 + u2 * 2;
                *(uint2*)(G1u + a) = make_uint2(lo, hi);
            }
        }
    }
}

// phaseB: unchanged from R12 (192 us floor of this structure; 7 experiments
// bracket it): asm-pinned B2 frags, full-XOR xA swizzle (0 conflicts),
// G1 coalesced uint2 prefetched at loop top, inline output head.
__global__ __launch_bounds__(512) __attribute__((amdgpu_waves_per_eu(2, 2)))
void phaseB(
    const uint_t* __restrict__ G1u, const ushort_t* __restrict__ N0m,
    const ushort_t* __restrict__ N1m, const float* __restrict__ nb1,
    const float* __restrict__ outW, const float* __restrict__ outb,
    float* __restrict__ out)
{
    __shared__ __align__(16) ushort_t w1s[16 * 512 * 8];  // 131072 B
    __shared__ __align__(16) ushort_t xA[16 * 512];       // [m][h1b0|h1b1|h2b0|h2b1]
    __shared__ __align__(16) float ghead[8][16];
    const int tid = threadIdx.x;
    const int wv = tid >> 6, l = tid & 63, l16 = l & 15, q = l >> 4;
    const int r0 = blockIdx.x * 16;
    const int u = wv * 16 + l16;                 // unit 0..127

    for (int i = tid; i < 8192; i += 512) ((uint4*)w1s)[i] = ((const uint4*)N0m)[i];
    for (int i = tid; i < 1024; i += 512) ((uint4*)xA)[i] = make_uint4(0, 0, 0, 0);

    // persistent L2-layer B-frags (128 regs)
    uintx4 B2[8][4];
#pragma unroll
    for (int kt = 0; kt < 8; ++kt)
#pragma unroll
        for (int g = 0; g < 4; ++g)
            B2[kt][g] = *(const uintx4*)(N1m + ((size_t)((kt * 4 + q) * 512 + g * 128 + u)) * 8);

    const float bI = nb1[u], bF = nb1[128 + u], bG = nb1[256 + u], bO = nb1[384 + u];
    const float ob = outb[0];
    const float owf = outW[u];
    float c1[4] = {0, 0, 0, 0}, c2[4] = {0, 0, 0, 0};

    const uint_t* g1base = G1u + (size_t)blockIdx.x * 48 * 4096;
    uint2 g1c[4], g1n[4];
#pragma unroll
    for (int r = 0; r < 4; ++r)
        g1c[r] = *(const uint2*)(g1base + (q * 4 + r) * 256 + u * 2);
    __syncthreads();

    const int kbW = u >> 3;   // 0..15
    const int jW = u & 7;

    for (int t = 0; t < 48; ++t) {
        const int cur = (t & 1) * 128;
        const int prv = cur ^ 128;

        // Residency pin: asm "modifies" B2 each iteration -> reload illegal.
#pragma unroll
        for (int kt = 0; kt < 8; ++kt)
#pragma unroll
            for (int g = 0; g < 4; ++g)
                asm volatile("" : "+v"(B2[kt][g]));

        // G1 prefetch for t+1 at loop top
        {
            int tn = (t < 47) ? t + 1 : 47;
            const uint_t* gp = g1base + (size_t)tn * 4096;
#pragma unroll
            for (int r = 0; r < 4; ++r)
                g1n[r] = *(const uint2*)(gp + (q * 4 + r) * 256 + u * 2);
        }

        // L1 MFMA: gates = Whh0 @ h1(t-1); A from xA[prv], B from LDS
        floatx4 acc[4] = {};
#pragma unroll
        for (int kt = 0; kt < 4; ++kt) {
            int kb = kt * 4 + q;
            int kbp = (kb ^ l16) & 15;
            half8_t a = *(const half8_t*)&xA[l16 * 512 + prv + kbp * 8];
#pragma unroll
            for (int g = 0; g < 4; ++g) {
                half8_t bfr = *(const half8_t*)&w1s[((size_t)(kb * 512 + g * 128 + u)) * 8];
                acc[g] = __builtin_amdgcn_mfma_f32_16x16x32_f16(a, bfr, acc[g], 0, 0, 0);
            }
        }
        // E1: gate + write h1(t) into buf cur
#pragma unroll
        for (int r = 0; r < 4; ++r) {
            float gi = acc[0][r] + h2f_lo(g1c[r].x);
            float gf = acc[1][r] + h2f_hi(g1c[r].x);
            float gg = acc[2][r] + h2f_lo(g1c[r].y);
            float go = acc[3][r] + h2f_hi(g1c[r].y);
            c1[r] = sigm(gf) * c1[r] + sigm(gi) * tanhx(gg);
            float h1 = sigm(go) * tanhx(c1[r]);
            int m = q * 4 + r;
            xA[m * 512 + cur + (((kbW ^ m) & 15) << 3) + jW] = f2h_bits(h1);
        }
        // L2 MFMA part A: kt 4..7 = h2(t-1) from xA[256+prv]
        floatx4 acc2[4] = {};
#pragma unroll
        for (int kt = 4; kt < 8; ++kt) {
            int kbr = (kt & 3) * 4 + q;
            int kbp = (kbr ^ l16) & 15;
            half8_t a = *(const half8_t*)&xA[l16 * 512 + 256 + prv + kbp * 8];
#pragma unroll
            for (int g = 0; g < 4; ++g)
                acc2[g] = __builtin_amdgcn_mfma_f32_16x16x32_f16(
                    a, __builtin_bit_cast(half8_t, B2[kt][g]), acc2[g], 0, 0, 0);
        }
        __syncthreads();   // #1: h1(t) visible

        // L2 MFMA part B: kt 0..3 = h1(t) from xA[cur]
#pragma unroll
        for (int kt = 0; kt < 4; ++kt) {
            int kb = kt * 4 + q;
            int kbp = (kb ^ l16) & 15;
            half8_t a = *(const half8_t*)&xA[l16 * 512 + cur + kbp * 8];
#pragma unroll
            for (int g = 0; g < 4; ++g)
                acc2[g] = __builtin_amdgcn_mfma_f32_16x16x32_f16(
                    a, __builtin_bit_cast(half8_t, B2[kt][g]), acc2[g], 0, 0, 0);
        }
        // E2: gate + write h2(t) + head partial from registers
        float p[4];
#pragma unroll
        for (int r = 0; r < 4; ++r) {
            float gi = acc2[0][r] + bI;
            float gf = acc2[1][r] + bF;
            float gg = acc2[2][r] + bG;
            float go = acc2[3][r] + bO;
            c2[r] = sigm(gf) * c2[r] + sigm(gi) * tanhx(gg);
            float h2 = sigm(go) * tanhx(c2[r]);
            int m = q * 4 + r;
            xA[m * 512 + 256 + cur + (((kbW ^ m) & 15) << 3) + jW] = f2h_bits(h2);
            p[r] = h2 * owf;
        }
#pragma unroll
        for (int mask = 1; mask < 16; mask <<= 1)
#pragma unroll
            for (int r = 0; r < 4; ++r) p[r] += __shfl_xor(p[r], mask, 64);
        if (l16 == 0) {
#pragma unroll
            for (int r = 0; r < 4; ++r) ghead[wv][q * 4 + r] = p[r];
        }
#pragma unroll
        for (int r = 0; r < 4; ++r) g1c[r] = g1n[r];
        __syncthreads();   // #2: h2(t) + ghead visible

        if (tid < 16) {
            float s = 0.0f;
#pragma unroll
            for (int w = 0; w < 8; ++w) s += ghead[w][tid];
            out[(r0 + tid) * 48 + t] = sigm(s + ob);
        }
    }
}

extern "C" void kernel_launch(void* const* d_in, const int* in_sizes, int n_in,
                              void* d_out, int out_size, void* d_ws, size_t ws_size,
                              hipStream_t stream)
{
    const float* note  = (const float*)d_in[0];
    const float* targ  = (const float*)d_in[1];
    const float* tWih0 = (const float*)d_in[2];
    const float* tb0   = (const float*)d_in[4];
    const float* tWih1 = (const float*)d_in[5];
    const float* tb1   = (const float*)d_in[7];
    const float* nWih0 = (const float*)d_in[8];
    const float* nWhh0 = (const float*)d_in[9];
    const float* nb0   = (const float*)d_in[10];
    const float* nWih1 = (const float*)d_in[11];
    const float* nWhh1 = (const float*)d_in[12];
    const float* nb1   = (const float*)d_in[13];
    const float* outW  = (const float*)d_in[14];
    const float* outb  = (const float*)d_in[15];

    char* ws = (char*)d_ws;
    uint_t*   G1u = (uint_t*)(ws);                // 64*48*4096 uints = 50331648 B
    ushort_t* W0m = (ushort_t*)(ws + 50331648);   //  98304 B
    ushort_t* W1m = (ushort_t*)(ws + 50429952);   // 393216 B
    ushort_t* N0x = (ushort_t*)(ws + 50823168);   // 262144 B
    ushort_t* N0m = (ushort_t*)(ws + 51085312);   // 131072 B
    ushort_t* N1m = (ushort_t*)(ws + 51216384);   // 262144 B

    packAll<<<2240, 256, 0, stream>>>(tWih0, tWih1, nWih0, nWhh0, nWih1, nWhh1,
                                      W0m, W1m, N0x, N0m, N1m);
    fusedA<<<1536, 512, 0, stream>>>(note, targ, W0m, tb0, W1m, tb1, N0x, nWih0, nb0, G1u);
    phaseB<<<64, 512, 0, stream>>>(G1u, N0m, N1m, nb1, outW, outb, (float*)d_out);
}